// Round 16
// baseline (287.735 us; speedup 1.0000x reference)
//
#include <hip/hip_runtime.h>
#include <stdint.h>
#include <math.h>

// JAX PRNG mode: 1 = threefry_partitionable (JAX >= 0.4.36 default), 0 = legacy/original.
#ifndef JAX_PARTITIONABLE
#define JAX_PARTITIONABLE 1
#endif

#define DIM    512
#define NTOT   32768
#define NMAJ   24576
#define NMIN   8192
#define NGEN   16384                       // NMIN * 2
#define XROWS  49152                       // NTOT + NGEN
#define Y_OFF  ((size_t)XROWS * DIM)       // 25165824

#define NSLICE 8
#define KSLICE 6
#define NCAND  (NSLICE * KSLICE)           // 48 candidates per row

// ws layout (float units):
//   [0, 8192)                         sq (fp32 norms)
//   [WS_H, +NMIN*DIM/2)               H  bf16 matrix (8192x512 ushort)
//   [WS_L, +NMIN*DIM/2)               (unused gap, kept for layout stability)
//   [WS_CAND_F, +NMIN*NCAND/2)        cand (ushort[NMIN][NCAND])
//   [WS_NBR_F, +NMIN*4)               nbr  (int[NMIN][4])
#define WS_H       (NMIN)
#define WS_L       (WS_H + NMIN * DIM / 2)
#define WS_CAND_F  (WS_L + NMIN * DIM / 2)
#define WS_NBR_F   (WS_CAND_F + NMIN * NCAND / 2)

typedef __attribute__((ext_vector_type(8))) short bfv8;
typedef __attribute__((ext_vector_type(4))) float f32x4;

// ---------------- threefry2x32 (Random123 / JAX schedule) ----------------
__device__ __forceinline__ void tf2x32(uint32_t k0, uint32_t k1,
                                       uint32_t x0, uint32_t x1,
                                       uint32_t &o0, uint32_t &o1) {
  const uint32_t ks2 = k0 ^ k1 ^ 0x1BD11BDAu;
  x0 += k0; x1 += k1;
#define TF_R(r) { x0 += x1; x1 = (x1 << (r)) | (x1 >> (32 - (r))); x1 ^= x0; }
  TF_R(13) TF_R(15) TF_R(26) TF_R(6)
  x0 += k1;  x1 += ks2 + 1u;
  TF_R(17) TF_R(29) TF_R(16) TF_R(24)
  x0 += ks2; x1 += k0 + 2u;
  TF_R(13) TF_R(15) TF_R(26) TF_R(6)
  x0 += k0;  x1 += k1 + 3u;
  TF_R(17) TF_R(29) TF_R(16) TF_R(24)
  x0 += k1;  x1 += ks2 + 4u;
  TF_R(13) TF_R(15) TF_R(26) TF_R(6)
  x0 += ks2; x1 += k0 + 5u;
#undef TF_R
  o0 = x0; o1 = x1;
}

#if JAX_PARTITIONABLE
__device__ __forceinline__ void jax_split(uint2 key, uint2 &c0, uint2 &c1) {
  tf2x32(key.x, key.y, 0u, 0u, c0.x, c0.y);
  tf2x32(key.x, key.y, 0u, 1u, c1.x, c1.y);
}
__device__ __forceinline__ uint32_t jax_bits(uint2 key, uint32_t f) {
  uint32_t a, b;
  tf2x32(key.x, key.y, 0u, f, a, b);
  return a ^ b;
}
#else
__device__ __forceinline__ void jax_split(uint2 key, uint2 &c0, uint2 &c1) {
  uint32_t a0, b0, a1, b1;
  tf2x32(key.x, key.y, 0u, 2u, a0, b0);
  tf2x32(key.x, key.y, 1u, 3u, a1, b1);
  c0 = make_uint2(a0, a1);
  c1 = make_uint2(b0, b1);
}
__device__ __forceinline__ uint32_t jax_bits(uint2 key, uint32_t f) {
  uint32_t a, b;
  if (f < (NGEN / 2)) { tf2x32(key.x, key.y, f, f + NGEN / 2, a, b); return a; }
  tf2x32(key.x, key.y, f - NGEN / 2, f, a, b); return b;
}
#endif

__device__ __forceinline__ void derive_keys(uint2 &k2, uint2 &k2i) {
  uint2 root = make_uint2(0u, 42u);
  uint2 dead, sub, k1;
  jax_split(root, dead, sub);
  jax_split(sub, k1, k2);
  jax_split(k1, dead, k2i);
}

// ---------------- kernel 0: fused prep — norms (fp64) + bf16 H -----------
__device__ __forceinline__ unsigned short f2bf(float x) {
  uint32_t u = __float_as_uint(x);
  uint32_t r = (u + 0x7FFFu + ((u >> 16) & 1u)) >> 16;   // RNE
  return (unsigned short)r;
}

__global__ __launch_bounds__(256) void prep_kernel(const float* __restrict__ X,
                                                   float* __restrict__ wsf) {
  const int row  = blockIdx.x * 4 + (threadIdx.x >> 6);
  const int lane = threadIdx.x & 63;
  const float* Xm = X + (size_t)NMAJ * DIM;
  const float4* p = reinterpret_cast<const float4*>(Xm + (size_t)row * DIM);
  ushort4* H4 = reinterpret_cast<ushort4*>(wsf + WS_H) + (size_t)row * 128;
  double s = 0.0;
#pragma unroll
  for (int q = 0; q < 2; ++q) {
    float4 v = p[lane + q * 64];
    ushort4 h;
    h.x = f2bf(v.x); h.y = f2bf(v.y); h.z = f2bf(v.z); h.w = f2bf(v.w);
    H4[lane + q * 64] = h;
    s += (double)v.x * v.x + (double)v.y * v.y + (double)v.z * v.z + (double)v.w * v.w;
  }
#pragma unroll
  for (int off = 32; off > 0; off >>= 1) s += __shfl_down(s, off);
  if (lane == 0) wsf[row] = (float)s;
}

// Branchless strict-< 5-deep insert, wave-guarded (R13-proven).
#define INSERT5B(TD, TI, dv, jv)                                           \
  { const bool b4 = (dv) < TD[4];                                          \
    if (__any(b4)) {                                                       \
      const bool b3 = (dv) < TD[3], b2 = (dv) < TD[2];                     \
      const bool b1 = (dv) < TD[1], b0 = (dv) < TD[0];                     \
      TD[4] = b3 ? TD[3] : (b4 ? (dv) : TD[4]);                            \
      TI[4] = b3 ? TI[3] : (b4 ? (jv) : TI[4]);                            \
      TD[3] = b2 ? TD[2] : (b3 ? (dv) : TD[3]);                            \
      TI[3] = b2 ? TI[2] : (b3 ? (jv) : TI[3]);                            \
      TD[2] = b1 ? TD[1] : (b2 ? (dv) : TD[2]);                            \
      TI[2] = b1 ? TI[1] : (b2 ? (jv) : TI[2]);                            \
      TD[1] = b0 ? TD[0] : (b1 ? (dv) : TD[1]);                            \
      TI[1] = b0 ? TI[0] : (b1 ? (jv) : TI[1]);                            \
      TD[0] = b0 ? (dv) : TD[0];                                           \
      TI[0] = b0 ? (jv) : TI[0];                                           \
    } }

// ---------------- kernel 1: single-bf16 MFMA syrk (R13-best, 130.5 us) ----
// grid = 512: e = bid>>6 (cand slice), n0 = (bid&63)*128. 64 steps =
// 4 ct-pairs x 16 ks; triple buffer 3x24KB, depth-2 prefetch, vmcnt(6) +
// one barrier/step, setprio around MFMA (exact R13-measured configuration;
// R14/R15 consolidation variants measured 134-135 -> reverted).
__global__ __launch_bounds__(256, 2) void smote_main(float* wsf) {
  __shared__ __align__(16) char raw[3 * 24576];   // 72 KB -> 2 blocks/CU

  const unsigned short* Hm = reinterpret_cast<const unsigned short*>(wsf + WS_H);

  const int tid = threadIdx.x;
  const int w  = tid >> 6;          // wave 0..3
  const int l  = tid & 63;          // lane
  const int wm = w & 1;             // M-quadrant (candidates)
  const int wn = w >> 1;            // N-quadrant (anchors)
  const int lg = l >> 4;            // 0..3
  const int ll = l & 15;

  const int e  = blockIdx.x >> 6;            // candidate slice 0..7
  const int n0 = (blockIdx.x & 63) * 128;    // anchor tile base

  // swizzled fragment LDS byte offsets (within a 24KB buffer)
  const int csw = (lg ^ ((ll >> 1) & 3)) * 16;
  int aoff[4], boff[4];
#pragma unroll
  for (int f = 0; f < 4; ++f) {
    aoff[f] = (wm * 64 + f * 16 + ll) * 64 + csw;            // A0; A1 = +8192
    boff[f] = 16384 + (wn * 64 + f * 16 + ll) * 64 + csw;    // B
  }

  // staging: lane -> row l>>2 (within 16-row block), swizzled source chunk
  const int srow   = l >> 2;
  const int schunk = ((l & 3) ^ ((l >> 3) & 3)) * 16;

  // stage step (cp2, ks2): A-pair (2x8KB) + B (8KB) into buffer bi, 6 loads
  auto STAGE = [&](int cp2, int ks2, int bi) {
    char* buf = raw + bi * 24576;
    const int kb = ks2 * 64;                 // byte offset within 1024B row
    const int jt = e * 1024 + cp2 * 256;
#pragma unroll
    for (int q = 0; q < 2; ++q) {
      const int rb = (q * 4 + w) * 16;       // 16-row block staged per inst
      const size_t roff = (size_t)(rb + srow) * 1024 + kb + schunk;
      const char* ga0 = (const char*)Hm + (size_t)jt * 1024 + roff;
      const char* ga1 = (const char*)Hm + (size_t)(jt + 128) * 1024 + roff;
      const char* gb  = (const char*)Hm + (size_t)n0 * 1024 + roff;
      __builtin_amdgcn_global_load_lds(
          (const __attribute__((address_space(1))) void*)ga0,
          (__attribute__((address_space(3))) void*)(buf + rb * 64), 16, 0, 0);
      __builtin_amdgcn_global_load_lds(
          (const __attribute__((address_space(1))) void*)ga1,
          (__attribute__((address_space(3))) void*)(buf + 8192 + rb * 64), 16, 0, 0);
      __builtin_amdgcn_global_load_lds(
          (const __attribute__((address_space(1))) void*)gb,
          (__attribute__((address_space(3))) void*)(buf + 16384 + rb * 64), 16, 0, 0);
    }
  };

  float td[4][5];
  int   ti_[4][5];
#pragma unroll
  for (int n = 0; n < 4; ++n)
#pragma unroll
    for (int s = 0; s < 5; ++s) { td[n][s] = 1e30f; ti_[n][s] = 0x7fffffff; }

  f32x4 accA[4][4], accB[4][4];
#pragma unroll
  for (int m = 0; m < 4; ++m)
#pragma unroll
    for (int n = 0; n < 4; ++n) {
      accA[m][n] = (f32x4){0.f, 0.f, 0.f, 0.f};
      accB[m][n] = (f32x4){0.f, 0.f, 0.f, 0.f};
    }

  STAGE(0, 0, 0);
  STAGE(0, 1, 1);

  int cur = 0;                 // buffer of step s
  int ks = 0, cp = 0;          // step-s coords
  int pks = 2, pcp = 0, pb = 2;// prefetch coords (step s+2) + its buffer

  for (int s = 0; s < 64; ++s) {
    // wait own step-s loads (6/wave; S(s+1)'s 6 stay in flight)
    asm volatile("s_waitcnt vmcnt(6)" ::: "memory");
    __builtin_amdgcn_s_barrier();            // tile s written by ALL waves
    __builtin_amdgcn_sched_barrier(0);

    // prefetch step s+2 into buf[(s+2)%3] (readers finished pre-barrier)
    STAGE(pcp, pks, pb);
    if (++pks == 16) { pks = 0; ++pcp; if (pcp == 4) pcp = 0; }  // wrap: stray tail
    if (++pb == 3) pb = 0;

    const char* buf = raw + cur * 24576;
    bfv8 bf[4], afA[4], afB[4];
#pragma unroll
    for (int n = 0; n < 4; ++n) bf[n]  = *reinterpret_cast<const bfv8*>(buf + boff[n]);
#pragma unroll
    for (int m = 0; m < 4; ++m) afA[m] = *reinterpret_cast<const bfv8*>(buf + aoff[m]);
#pragma unroll
    for (int m = 0; m < 4; ++m) afB[m] = *reinterpret_cast<const bfv8*>(buf + 8192 + aoff[m]);

    __builtin_amdgcn_s_setprio(1);
#pragma unroll
    for (int m = 0; m < 4; ++m)
#pragma unroll
      for (int n = 0; n < 4; ++n)
        accA[m][n] = __builtin_amdgcn_mfma_f32_16x16x32_bf16(afA[m], bf[n], accA[m][n], 0, 0, 0);
#pragma unroll
    for (int m = 0; m < 4; ++m)
#pragma unroll
      for (int n = 0; n < 4; ++n)
        accB[m][n] = __builtin_amdgcn_mfma_f32_16x16x32_bf16(afB[m], bf[n], accB[m][n], 0, 0, 0);
    __builtin_amdgcn_s_setprio(0);

    if (ks == 15) {
      // epilogue for this ct-pair: metric = sq[j] - 2*dot; stable top-5.
      // C/D layout (m89): col = lane&15 (anchor), row = (lane>>4)*4+reg (cand)
      const int jt = e * 1024 + cp * 256;
#pragma unroll
      for (int m = 0; m < 4; ++m) {
        const int jb = jt + wm * 64 + m * 16 + lg * 4;
        const float4 mj = *reinterpret_cast<const float4*>(&wsf[jb]);
        const float mjr[4] = {mj.x, mj.y, mj.z, mj.w};
#pragma unroll
        for (int r = 0; r < 4; ++r) {
#pragma unroll
          for (int n = 0; n < 4; ++n) {
            const float mv = mjr[r] - 2.0f * accA[m][n][r];
            INSERT5B(td[n], ti_[n], mv, jb + r);
          }
        }
      }
#pragma unroll
      for (int m = 0; m < 4; ++m) {
        const int jb = jt + 128 + wm * 64 + m * 16 + lg * 4;
        const float4 mj = *reinterpret_cast<const float4*>(&wsf[jb]);
        const float mjr[4] = {mj.x, mj.y, mj.z, mj.w};
#pragma unroll
        for (int r = 0; r < 4; ++r) {
#pragma unroll
          for (int n = 0; n < 4; ++n) {
            const float mv = mjr[r] - 2.0f * accB[m][n][r];
            INSERT5B(td[n], ti_[n], mv, jb + r);
          }
        }
      }
#pragma unroll
      for (int m = 0; m < 4; ++m)
#pragma unroll
        for (int n = 0; n < 4; ++n) {
          accA[m][n] = (f32x4){0.f, 0.f, 0.f, 0.f};
          accB[m][n] = (f32x4){0.f, 0.f, 0.f, 0.f};
        }
    }
    if (++ks == 16) { ks = 0; ++cp; }
    if (++cur == 3) cur = 0;
  }

  // drain stray prefetches before reusing LDS for the merge
  asm volatile("s_waitcnt vmcnt(0)" ::: "memory");
  __syncthreads();

  // block merge: per anchor col, 8 lists (2 wm x 4 lg) of 5 -> top-6/slice
  float* md = reinterpret_cast<float*>(raw);            // [40][128]
  int*   mi = reinterpret_cast<int*>(raw + 20480);      // [40][128]
  const int lid = wm * 4 + lg;                          // 0..7
#pragma unroll
  for (int n = 0; n < 4; ++n) {
    const int col = wn * 64 + n * 16 + ll;
#pragma unroll
    for (int s = 0; s < 5; ++s) {
      md[(lid * 5 + s) * 128 + col] = td[n][s];
      mi[(lid * 5 + s) * 128 + col] = ti_[n][s];
    }
  }
  __syncthreads();
  if (tid < 128) {
    unsigned short* cand = reinterpret_cast<unsigned short*>(wsf + WS_CAND_F)
                         + (size_t)(n0 + tid) * NCAND + e * KSLICE;
    float ld = -1e31f; int li = -1;
    for (int s = 0; s < KSLICE; ++s) {
      float bd = 1e30f; int bi = 0x7fffffff;
      for (int c = 0; c < 40; ++c) {
        const float d = md[c * 128 + tid];
        const int  ix = mi[c * 128 + tid];
        const bool gt_last = (d > ld) || (d == ld && ix > li);
        const bool lt_best = (d < bd) || (d == bd && ix < bi);
        if (gt_last && lt_best) { bd = d; bi = ix; }
      }
      ld = bd; li = bi;
      cand[s] = (unsigned short)bi;
    }
  }
}

// ---------------- kernel 2: fused rerank + X/y passthrough ----------------
// Interleaved co-scheduling: even bid = rerank row-group (wave-per-row,
// latency/VALU-bound), odd bid = copy chunk (pure BW). Both paths use ~48
// VGPR -> full co-residency; the copy's HBM streaming hides under rerank's
// shuffle/gather latency instead of running serially afterwards.
__global__ __launch_bounds__(256) void rerank_copy_kernel(const float* __restrict__ X,
                                                          const int* __restrict__ y,
                                                          float* __restrict__ wsf,
                                                          float* __restrict__ out) {
  const int bid = blockIdx.x;
  if ((bid & 1) == 0) {
    // ---- rerank: 4 rows per block, one wave per row (R12-proven) ----
    __shared__ unsigned long long keys_s[4][NCAND];
    const float* Xm = X + (size_t)NMAJ * DIM;
    const int wave = threadIdx.x >> 6;
    const int lane = threadIdx.x & 63;
    const int row  = (bid >> 1) * 4 + wave;

    const unsigned short* cand = reinterpret_cast<const unsigned short*>(wsf + WS_CAND_F)
                               + (size_t)row * NCAND;
    const float si = wsf[row];
    const float4* Xi = reinterpret_cast<const float4*>(Xm + (size_t)row * DIM);
    const float4 xi0 = Xi[lane], xi1 = Xi[lane + 64];

    const int jv = (lane < NCAND) ? (int)cand[lane] : 0;

#pragma unroll 4
    for (int c = 0; c < NCAND; ++c) {
      const int j = __shfl(jv, c);
      const float4* Xj = reinterpret_cast<const float4*>(Xm + (size_t)j * DIM);
      const float4 xj0 = Xj[lane], xj1 = Xj[lane + 64];
      double s = (double)xi0.x * xj0.x + (double)xi0.y * xj0.y
               + (double)xi0.z * xj0.z + (double)xi0.w * xj0.w
               + (double)xi1.x * xj1.x + (double)xi1.y * xj1.y
               + (double)xi1.z * xj1.z + (double)xi1.w * xj1.w;
#pragma unroll
      for (int off = 32; off > 0; off >>= 1) s += __shfl_down(s, off);
      if (lane == 0) {
        const float d2 = (si + wsf[j]) - 2.0f * (float)s;      // reference fp32 chain
        const float d  = (float)sqrt((double)fmaxf(d2, 0.0f)); // correctly-rounded
        keys_s[wave][c] = ((unsigned long long)__float_as_uint(d) << 32) | (uint32_t)j;
      }
    }

    unsigned long long key = (lane < NCAND) ? keys_s[wave][lane] : ~0ull;
    int* nbr = reinterpret_cast<int*>(wsf) + WS_NBR_F + (size_t)row * 4;
#pragma unroll
    for (int s = 0; s < 5; ++s) {          // round 0 = self (D == 0)
      unsigned long long k = key;
#pragma unroll
      for (int off = 32; off > 0; off >>= 1) {
        const unsigned long long o = __shfl_xor(k, off);
        if (o < k) k = o;
      }
      if (key == k) key = ~0ull;           // mask winner (keys unique: idx unique)
      if (s >= 1 && lane == 0) nbr[s - 1] = (int)(k & 0xffffffffu);
    }
  } else {
    // ---- copy: passthrough X + y_out (independent of rerank) ----
    const long long XF4 = (long long)NTOT * DIM / 4;   // 4194304
    const long long YF4 = XROWS / 4;                   // 12288
    long long idx = (long long)(bid >> 1) * 256 + threadIdx.x;
    const long long stride = (long long)(gridDim.x >> 1) * 256;
    for (long long i = idx; i < XF4 + YF4; i += stride) {
      if (i < XF4) {
        reinterpret_cast<float4*>(out)[i] = reinterpret_cast<const float4*>(X)[i];
      } else {
        long long j = i - XF4;
        float4 o;
        if (j < NTOT / 4) {
          int4 yv = reinterpret_cast<const int4*>(y)[j];
          o.x = (float)yv.x; o.y = (float)yv.y; o.z = (float)yv.z; o.w = (float)yv.w;
        } else {
          o.x = o.y = o.z = o.w = 1.0f;
        }
        reinterpret_cast<float4*>(out + Y_OFF)[j] = o;
      }
    }
  }
}

// ---------------- kernel 3: threefry + generate rows ---------------------
__global__ __launch_bounds__(256) void gen_kernel(const float* __restrict__ X,
                                                  const float* __restrict__ wsf,
                                                  float* __restrict__ out) {
  __shared__ int   nbr_s[32][4];
  __shared__ float u_s[64];
  __shared__ int   nb_s[64];
  const float* Xm = X + (size_t)NMAJ * DIM;
  const int r0 = blockIdx.x * 32;
  const int tid = threadIdx.x;

  if (tid < 32) {
    const int* nb = reinterpret_cast<const int*>(wsf) + WS_NBR_F + (size_t)(r0 + tid) * 4;
#pragma unroll
    for (int s = 0; s < 4; ++s) nbr_s[tid][s] = nb[s];
  }
  __syncthreads();
  if (tid < 64) {
    uint2 k2, k2i;
    derive_keys(k2, k2i);
    const uint32_t f = (uint32_t)(2 * r0 + tid);      // flat index into (8192,2)
    const uint32_t ch = jax_bits(k2i, f) & 3u;        // randint(0,4)
    nb_s[tid] = nbr_s[tid >> 1][ch];
    const uint32_t ub = jax_bits(k2, f);
    u_s[tid] = __uint_as_float((ub >> 9) | 0x3f800000u) - 1.0f;
  }
  __syncthreads();

  const int c = tid * 2;
  for (int g = 0; g < 64; ++g) {
    const int i = g >> 1;
    const float u = u_s[g];
    const int nb = nb_s[g];
    float2 bv = *reinterpret_cast<const float2*>(Xm + (size_t)(r0 + i) * DIM + c);
    float2 nv = *reinterpret_cast<const float2*>(Xm + (size_t)nb * DIM + c);
    float2 o;
    o.x = bv.x + u * (nv.x - bv.x);
    o.y = bv.y + u * (nv.y - bv.y);
    *reinterpret_cast<float2*>(out + ((size_t)(NTOT + 2 * r0 + g)) * DIM + c) = o;
  }
}

extern "C" void kernel_launch(void* const* d_in, const int* in_sizes, int n_in,
                              void* d_out, int out_size, void* d_ws, size_t ws_size,
                              hipStream_t stream) {
  const float* X = (const float*)d_in[0];
  const int*   y = (const int*)d_in[1];
  float* out = (float*)d_out;
  float* wsf = (float*)d_ws;
  (void)in_sizes; (void)n_in; (void)out_size; (void)ws_size;

  prep_kernel       <<<dim3(NMIN / 4), dim3(256), 0, stream>>>(X, wsf);
  smote_main        <<<dim3(512),      dim3(256), 0, stream>>>(wsf);
  rerank_copy_kernel<<<dim3(4096),     dim3(256), 0, stream>>>(X, y, wsf, out);
  gen_kernel        <<<dim3(NMIN / 32), dim3(256), 0, stream>>>(X, wsf, out);
}

// Round 17
// 240.625 us; speedup vs baseline: 1.1958x; 1.1958x over previous
//
#include <hip/hip_runtime.h>
#include <stdint.h>
#include <math.h>

// JAX PRNG mode: 1 = threefry_partitionable (JAX >= 0.4.36 default), 0 = legacy/original.
#ifndef JAX_PARTITIONABLE
#define JAX_PARTITIONABLE 1
#endif

#define DIM    512
#define NTOT   32768
#define NMAJ   24576
#define NMIN   8192
#define NGEN   16384                       // NMIN * 2
#define XROWS  49152                       // NTOT + NGEN
#define Y_OFF  ((size_t)XROWS * DIM)       // 25165824

#define NSLICE 8
#define KSLICE 6
#define NCAND  (NSLICE * KSLICE)           // 48 candidates per row

// ws layout (float units):
//   [0, 8192)                         sq (fp32 norms)
//   [WS_H, +NMIN*DIM/2)               H  bf16 matrix (8192x512 ushort)
//   [WS_L, +NMIN*DIM/2)               (unused gap, kept for layout stability)
//   [WS_CAND_F, +NMIN*NCAND/2)        cand (ushort[NMIN][NCAND])
#define WS_H       (NMIN)
#define WS_L       (WS_H + NMIN * DIM / 2)
#define WS_CAND_F  (WS_L + NMIN * DIM / 2)

typedef __attribute__((ext_vector_type(8))) short bfv8;
typedef __attribute__((ext_vector_type(4))) float f32x4;

// ---------------- threefry2x32 (Random123 / JAX schedule) ----------------
__device__ __forceinline__ void tf2x32(uint32_t k0, uint32_t k1,
                                       uint32_t x0, uint32_t x1,
                                       uint32_t &o0, uint32_t &o1) {
  const uint32_t ks2 = k0 ^ k1 ^ 0x1BD11BDAu;
  x0 += k0; x1 += k1;
#define TF_R(r) { x0 += x1; x1 = (x1 << (r)) | (x1 >> (32 - (r))); x1 ^= x0; }
  TF_R(13) TF_R(15) TF_R(26) TF_R(6)
  x0 += k1;  x1 += ks2 + 1u;
  TF_R(17) TF_R(29) TF_R(16) TF_R(24)
  x0 += ks2; x1 += k0 + 2u;
  TF_R(13) TF_R(15) TF_R(26) TF_R(6)
  x0 += k0;  x1 += k1 + 3u;
  TF_R(17) TF_R(29) TF_R(16) TF_R(24)
  x0 += k1;  x1 += ks2 + 4u;
  TF_R(13) TF_R(15) TF_R(26) TF_R(6)
  x0 += ks2; x1 += k0 + 5u;
#undef TF_R
  o0 = x0; o1 = x1;
}

#if JAX_PARTITIONABLE
__device__ __forceinline__ void jax_split(uint2 key, uint2 &c0, uint2 &c1) {
  tf2x32(key.x, key.y, 0u, 0u, c0.x, c0.y);
  tf2x32(key.x, key.y, 0u, 1u, c1.x, c1.y);
}
__device__ __forceinline__ uint32_t jax_bits(uint2 key, uint32_t f) {
  uint32_t a, b;
  tf2x32(key.x, key.y, 0u, f, a, b);
  return a ^ b;
}
#else
__device__ __forceinline__ void jax_split(uint2 key, uint2 &c0, uint2 &c1) {
  uint32_t a0, b0, a1, b1;
  tf2x32(key.x, key.y, 0u, 2u, a0, b0);
  tf2x32(key.x, key.y, 1u, 3u, a1, b1);
  c0 = make_uint2(a0, a1);
  c1 = make_uint2(b0, b1);
}
__device__ __forceinline__ uint32_t jax_bits(uint2 key, uint32_t f) {
  uint32_t a, b;
  if (f < (NGEN / 2)) { tf2x32(key.x, key.y, f, f + NGEN / 2, a, b); return a; }
  tf2x32(key.x, key.y, f - NGEN / 2, f, a, b); return b;
}
#endif

__device__ __forceinline__ void derive_keys(uint2 &k2, uint2 &k2i) {
  uint2 root = make_uint2(0u, 42u);
  uint2 dead, sub, k1;
  jax_split(root, dead, sub);
  jax_split(sub, k1, k2);
  jax_split(k1, dead, k2i);
}

// ---------------- kernel 0: fused prep — norms (fp64) + bf16 H -----------
__device__ __forceinline__ unsigned short f2bf(float x) {
  uint32_t u = __float_as_uint(x);
  uint32_t r = (u + 0x7FFFu + ((u >> 16) & 1u)) >> 16;   // RNE
  return (unsigned short)r;
}

__global__ __launch_bounds__(256) void prep_kernel(const float* __restrict__ X,
                                                   float* __restrict__ wsf) {
  const int row  = blockIdx.x * 4 + (threadIdx.x >> 6);
  const int lane = threadIdx.x & 63;
  const float* Xm = X + (size_t)NMAJ * DIM;
  const float4* p = reinterpret_cast<const float4*>(Xm + (size_t)row * DIM);
  ushort4* H4 = reinterpret_cast<ushort4*>(wsf + WS_H) + (size_t)row * 128;
  double s = 0.0;
#pragma unroll
  for (int q = 0; q < 2; ++q) {
    float4 v = p[lane + q * 64];
    ushort4 h;
    h.x = f2bf(v.x); h.y = f2bf(v.y); h.z = f2bf(v.z); h.w = f2bf(v.w);
    H4[lane + q * 64] = h;
    s += (double)v.x * v.x + (double)v.y * v.y + (double)v.z * v.z + (double)v.w * v.w;
  }
#pragma unroll
  for (int off = 32; off > 0; off >>= 1) s += __shfl_down(s, off);
  if (lane == 0) wsf[row] = (float)s;
}

// Branchless strict-< 5-deep insert, wave-guarded (R13-proven).
#define INSERT5B(TD, TI, dv, jv)                                           \
  { const bool b4 = (dv) < TD[4];                                          \
    if (__any(b4)) {                                                       \
      const bool b3 = (dv) < TD[3], b2 = (dv) < TD[2];                     \
      const bool b1 = (dv) < TD[1], b0 = (dv) < TD[0];                     \
      TD[4] = b3 ? TD[3] : (b4 ? (dv) : TD[4]);                            \
      TI[4] = b3 ? TI[3] : (b4 ? (jv) : TI[4]);                            \
      TD[3] = b2 ? TD[2] : (b3 ? (dv) : TD[3]);                            \
      TI[3] = b2 ? TI[2] : (b3 ? (jv) : TI[3]);                            \
      TD[2] = b1 ? TD[1] : (b2 ? (dv) : TD[2]);                            \
      TI[2] = b1 ? TI[1] : (b2 ? (jv) : TI[2]);                            \
      TD[1] = b0 ? TD[0] : (b1 ? (dv) : TD[1]);                            \
      TI[1] = b0 ? TI[0] : (b1 ? (jv) : TI[1]);                            \
      TD[0] = b0 ? (dv) : TD[0];                                           \
      TI[0] = b0 ? (jv) : TI[0];                                           \
    } }

// ---------------- kernel 1: single-bf16 MFMA syrk (R13-best, 130.5 us) ----
// grid = 512: e = bid>>6 (cand slice), n0 = (bid&63)*128. 64 steps =
// 4 ct-pairs x 16 ks; triple buffer 3x24KB, depth-2 prefetch, vmcnt(6) +
// one barrier/step, setprio around MFMA (exact R13-measured configuration).
__global__ __launch_bounds__(256, 2) void smote_main(float* wsf) {
  __shared__ __align__(16) char raw[3 * 24576];   // 72 KB -> 2 blocks/CU

  const unsigned short* Hm = reinterpret_cast<const unsigned short*>(wsf + WS_H);

  const int tid = threadIdx.x;
  const int w  = tid >> 6;          // wave 0..3
  const int l  = tid & 63;          // lane
  const int wm = w & 1;             // M-quadrant (candidates)
  const int wn = w >> 1;            // N-quadrant (anchors)
  const int lg = l >> 4;            // 0..3
  const int ll = l & 15;

  const int e  = blockIdx.x >> 6;            // candidate slice 0..7
  const int n0 = (blockIdx.x & 63) * 128;    // anchor tile base

  // swizzled fragment LDS byte offsets (within a 24KB buffer)
  const int csw = (lg ^ ((ll >> 1) & 3)) * 16;
  int aoff[4], boff[4];
#pragma unroll
  for (int f = 0; f < 4; ++f) {
    aoff[f] = (wm * 64 + f * 16 + ll) * 64 + csw;            // A0; A1 = +8192
    boff[f] = 16384 + (wn * 64 + f * 16 + ll) * 64 + csw;    // B
  }

  // staging: lane -> row l>>2 (within 16-row block), swizzled source chunk
  const int srow   = l >> 2;
  const int schunk = ((l & 3) ^ ((l >> 3) & 3)) * 16;

  // stage step (cp2, ks2): A-pair (2x8KB) + B (8KB) into buffer bi, 6 loads
  auto STAGE = [&](int cp2, int ks2, int bi) {
    char* buf = raw + bi * 24576;
    const int kb = ks2 * 64;                 // byte offset within 1024B row
    const int jt = e * 1024 + cp2 * 256;
#pragma unroll
    for (int q = 0; q < 2; ++q) {
      const int rb = (q * 4 + w) * 16;       // 16-row block staged per inst
      const size_t roff = (size_t)(rb + srow) * 1024 + kb + schunk;
      const char* ga0 = (const char*)Hm + (size_t)jt * 1024 + roff;
      const char* ga1 = (const char*)Hm + (size_t)(jt + 128) * 1024 + roff;
      const char* gb  = (const char*)Hm + (size_t)n0 * 1024 + roff;
      __builtin_amdgcn_global_load_lds(
          (const __attribute__((address_space(1))) void*)ga0,
          (__attribute__((address_space(3))) void*)(buf + rb * 64), 16, 0, 0);
      __builtin_amdgcn_global_load_lds(
          (const __attribute__((address_space(1))) void*)ga1,
          (__attribute__((address_space(3))) void*)(buf + 8192 + rb * 64), 16, 0, 0);
      __builtin_amdgcn_global_load_lds(
          (const __attribute__((address_space(1))) void*)gb,
          (__attribute__((address_space(3))) void*)(buf + 16384 + rb * 64), 16, 0, 0);
    }
  };

  float td[4][5];
  int   ti_[4][5];
#pragma unroll
  for (int n = 0; n < 4; ++n)
#pragma unroll
    for (int s = 0; s < 5; ++s) { td[n][s] = 1e30f; ti_[n][s] = 0x7fffffff; }

  f32x4 accA[4][4], accB[4][4];
#pragma unroll
  for (int m = 0; m < 4; ++m)
#pragma unroll
    for (int n = 0; n < 4; ++n) {
      accA[m][n] = (f32x4){0.f, 0.f, 0.f, 0.f};
      accB[m][n] = (f32x4){0.f, 0.f, 0.f, 0.f};
    }

  STAGE(0, 0, 0);
  STAGE(0, 1, 1);

  int cur = 0;                 // buffer of step s
  int ks = 0, cp = 0;          // step-s coords
  int pks = 2, pcp = 0, pb = 2;// prefetch coords (step s+2) + its buffer

  for (int s = 0; s < 64; ++s) {
    // wait own step-s loads (6/wave; S(s+1)'s 6 stay in flight)
    asm volatile("s_waitcnt vmcnt(6)" ::: "memory");
    __builtin_amdgcn_s_barrier();            // tile s written by ALL waves
    __builtin_amdgcn_sched_barrier(0);

    // prefetch step s+2 into buf[(s+2)%3] (readers finished pre-barrier)
    STAGE(pcp, pks, pb);
    if (++pks == 16) { pks = 0; ++pcp; if (pcp == 4) pcp = 0; }  // wrap: stray tail
    if (++pb == 3) pb = 0;

    const char* buf = raw + cur * 24576;
    bfv8 bf[4], afA[4], afB[4];
#pragma unroll
    for (int n = 0; n < 4; ++n) bf[n]  = *reinterpret_cast<const bfv8*>(buf + boff[n]);
#pragma unroll
    for (int m = 0; m < 4; ++m) afA[m] = *reinterpret_cast<const bfv8*>(buf + aoff[m]);
#pragma unroll
    for (int m = 0; m < 4; ++m) afB[m] = *reinterpret_cast<const bfv8*>(buf + 8192 + aoff[m]);

    __builtin_amdgcn_s_setprio(1);
#pragma unroll
    for (int m = 0; m < 4; ++m)
#pragma unroll
      for (int n = 0; n < 4; ++n)
        accA[m][n] = __builtin_amdgcn_mfma_f32_16x16x32_bf16(afA[m], bf[n], accA[m][n], 0, 0, 0);
#pragma unroll
    for (int m = 0; m < 4; ++m)
#pragma unroll
      for (int n = 0; n < 4; ++n)
        accB[m][n] = __builtin_amdgcn_mfma_f32_16x16x32_bf16(afB[m], bf[n], accB[m][n], 0, 0, 0);
    __builtin_amdgcn_s_setprio(0);

    if (ks == 15) {
      // epilogue for this ct-pair: metric = sq[j] - 2*dot; stable top-5.
      // C/D layout (m89): col = lane&15 (anchor), row = (lane>>4)*4+reg (cand)
      const int jt = e * 1024 + cp * 256;
#pragma unroll
      for (int m = 0; m < 4; ++m) {
        const int jb = jt + wm * 64 + m * 16 + lg * 4;
        const float4 mj = *reinterpret_cast<const float4*>(&wsf[jb]);
        const float mjr[4] = {mj.x, mj.y, mj.z, mj.w};
#pragma unroll
        for (int r = 0; r < 4; ++r) {
#pragma unroll
          for (int n = 0; n < 4; ++n) {
            const float mv = mjr[r] - 2.0f * accA[m][n][r];
            INSERT5B(td[n], ti_[n], mv, jb + r);
          }
        }
      }
#pragma unroll
      for (int m = 0; m < 4; ++m) {
        const int jb = jt + 128 + wm * 64 + m * 16 + lg * 4;
        const float4 mj = *reinterpret_cast<const float4*>(&wsf[jb]);
        const float mjr[4] = {mj.x, mj.y, mj.z, mj.w};
#pragma unroll
        for (int r = 0; r < 4; ++r) {
#pragma unroll
          for (int n = 0; n < 4; ++n) {
            const float mv = mjr[r] - 2.0f * accB[m][n][r];
            INSERT5B(td[n], ti_[n], mv, jb + r);
          }
        }
      }
#pragma unroll
      for (int m = 0; m < 4; ++m)
#pragma unroll
        for (int n = 0; n < 4; ++n) {
          accA[m][n] = (f32x4){0.f, 0.f, 0.f, 0.f};
          accB[m][n] = (f32x4){0.f, 0.f, 0.f, 0.f};
        }
    }
    if (++ks == 16) { ks = 0; ++cp; }
    if (++cur == 3) cur = 0;
  }

  // drain stray prefetches before reusing LDS for the merge
  asm volatile("s_waitcnt vmcnt(0)" ::: "memory");
  __syncthreads();

  // block merge: per anchor col, 8 lists (2 wm x 4 lg) of 5 -> top-6/slice
  float* md = reinterpret_cast<float*>(raw);            // [40][128]
  int*   mi = reinterpret_cast<int*>(raw + 20480);      // [40][128]
  const int lid = wm * 4 + lg;                          // 0..7
#pragma unroll
  for (int n = 0; n < 4; ++n) {
    const int col = wn * 64 + n * 16 + ll;
#pragma unroll
    for (int s = 0; s < 5; ++s) {
      md[(lid * 5 + s) * 128 + col] = td[n][s];
      mi[(lid * 5 + s) * 128 + col] = ti_[n][s];
    }
  }
  __syncthreads();
  if (tid < 128) {
    unsigned short* cand = reinterpret_cast<unsigned short*>(wsf + WS_CAND_F)
                         + (size_t)(n0 + tid) * NCAND + e * KSLICE;
    float ld = -1e31f; int li = -1;
    for (int s = 0; s < KSLICE; ++s) {
      float bd = 1e30f; int bi = 0x7fffffff;
      for (int c = 0; c < 40; ++c) {
        const float d = md[c * 128 + tid];
        const int  ix = mi[c * 128 + tid];
        const bool gt_last = (d > ld) || (d == ld && ix > li);
        const bool lt_best = (d < bd) || (d == bd && ix < bi);
        if (gt_last && lt_best) { bd = d; bi = ix; }
      }
      ld = bd; li = bi;
      cand[s] = (unsigned short)bi;
    }
  }
}

// ---------------- kernel 2: fused rerank + gen (dependency-local) ---------
// Phase 1 = R12-proven rerank (one wave per row, 4 rows/block). Phase 2 =
// generate this block's 8 synthetic rows directly from the LDS nbr values —
// no global nbr round-trip, no separate dependent launch. NOT co-scheduled
// with streaming copy (R16 lesson: BW-flood inflates gather latency).
__global__ __launch_bounds__(256) void rerank_gen_kernel(const float* __restrict__ X,
                                                         float* __restrict__ wsf,
                                                         float* __restrict__ out) {
  __shared__ unsigned long long keys_s[4][NCAND];
  __shared__ int   nbr_s[4][4];
  __shared__ float u_s[8];
  __shared__ int   nb_s[8];
  const float* Xm = X + (size_t)NMAJ * DIM;
  const int wave = threadIdx.x >> 6;
  const int lane = threadIdx.x & 63;
  const int r0b  = blockIdx.x * 4;
  const int row  = r0b + wave;

  const unsigned short* cand = reinterpret_cast<const unsigned short*>(wsf + WS_CAND_F)
                             + (size_t)row * NCAND;
  const float si = wsf[row];
  const float4* Xi = reinterpret_cast<const float4*>(Xm + (size_t)row * DIM);
  const float4 xi0 = Xi[lane], xi1 = Xi[lane + 64];

  const int jv = (lane < NCAND) ? (int)cand[lane] : 0;

#pragma unroll 4
  for (int c = 0; c < NCAND; ++c) {
    const int j = __shfl(jv, c);
    const float4* Xj = reinterpret_cast<const float4*>(Xm + (size_t)j * DIM);
    const float4 xj0 = Xj[lane], xj1 = Xj[lane + 64];
    double s = (double)xi0.x * xj0.x + (double)xi0.y * xj0.y
             + (double)xi0.z * xj0.z + (double)xi0.w * xj0.w
             + (double)xi1.x * xj1.x + (double)xi1.y * xj1.y
             + (double)xi1.z * xj1.z + (double)xi1.w * xj1.w;
#pragma unroll
    for (int off = 32; off > 0; off >>= 1) s += __shfl_down(s, off);
    if (lane == 0) {
      const float d2 = (si + wsf[j]) - 2.0f * (float)s;      // reference fp32 chain
      const float d  = (float)sqrt((double)fmaxf(d2, 0.0f)); // correctly-rounded
      keys_s[wave][c] = ((unsigned long long)__float_as_uint(d) << 32) | (uint32_t)j;
    }
  }

  unsigned long long key = (lane < NCAND) ? keys_s[wave][lane] : ~0ull;
#pragma unroll
  for (int s = 0; s < 5; ++s) {          // round 0 = self (D == 0)
    unsigned long long k = key;
#pragma unroll
    for (int off = 32; off > 0; off >>= 1) {
      const unsigned long long o = __shfl_xor(k, off);
      if (o < k) k = o;
    }
    if (key == k) key = ~0ull;           // mask winner (keys unique: idx unique)
    if (s >= 1 && lane == 0) nbr_s[wave][s - 1] = (int)(k & 0xffffffffu);
  }
  __syncthreads();

  // threefry for the block's 8 flat indices f = 2*r0b + g
  if (threadIdx.x < 8) {
    uint2 k2, k2i;
    derive_keys(k2, k2i);
    const uint32_t f = (uint32_t)(2 * r0b + threadIdx.x);
    const uint32_t ch = jax_bits(k2i, f) & 3u;        // randint(0,4)
    nb_s[threadIdx.x] = nbr_s[threadIdx.x >> 1][ch];
    const uint32_t ub = jax_bits(k2, f);
    u_s[threadIdx.x] = __uint_as_float((ub >> 9) | 0x3f800000u) - 1.0f;
  }
  __syncthreads();

  // generate: 32 threads per synthetic row, 16 floats each
  const int g  = threadIdx.x >> 5;                    // 0..7
  const int cb = (threadIdx.x & 31) * 16;             // col base (floats)
  const float u = u_s[g];
  const int  nb = nb_s[g];
  const int  ai = r0b + (g >> 1);
  const float4* bp = reinterpret_cast<const float4*>(Xm + (size_t)ai * DIM + cb);
  const float4* np = reinterpret_cast<const float4*>(Xm + (size_t)nb * DIM + cb);
  float4* op = reinterpret_cast<float4*>(out + (size_t)(NTOT + 2 * r0b + g) * DIM + cb);
#pragma unroll
  for (int q = 0; q < 4; ++q) {
    const float4 b = bp[q], nv = np[q];
    float4 o;
    o.x = b.x + u * (nv.x - b.x);
    o.y = b.y + u * (nv.y - b.y);
    o.z = b.z + u * (nv.z - b.z);
    o.w = b.w + u * (nv.w - b.w);
    op[q] = o;
  }
}

// ---------------- kernel 3: passthrough X + y_out (pure streaming) --------
__global__ __launch_bounds__(256) void copy_kernel(const float* __restrict__ X,
                                                   const int* __restrict__ y,
                                                   float* __restrict__ out) {
  const long long XF4 = (long long)NTOT * DIM / 4;   // 4194304
  const long long YF4 = XROWS / 4;                   // 12288
  long long idx = (long long)blockIdx.x * blockDim.x + threadIdx.x;
  const long long stride = (long long)gridDim.x * blockDim.x;
  for (long long i = idx; i < XF4 + YF4; i += stride) {
    if (i < XF4) {
      reinterpret_cast<float4*>(out)[i] = reinterpret_cast<const float4*>(X)[i];
    } else {
      long long j = i - XF4;
      float4 o;
      if (j < NTOT / 4) {
        int4 yv = reinterpret_cast<const int4*>(y)[j];
        o.x = (float)yv.x; o.y = (float)yv.y; o.z = (float)yv.z; o.w = (float)yv.w;
      } else {
        o.x = o.y = o.z = o.w = 1.0f;
      }
      reinterpret_cast<float4*>(out + Y_OFF)[j] = o;
    }
  }
}

extern "C" void kernel_launch(void* const* d_in, const int* in_sizes, int n_in,
                              void* d_out, int out_size, void* d_ws, size_t ws_size,
                              hipStream_t stream) {
  const float* X = (const float*)d_in[0];
  const int*   y = (const int*)d_in[1];
  float* out = (float*)d_out;
  float* wsf = (float*)d_ws;
  (void)in_sizes; (void)n_in; (void)out_size; (void)ws_size;

  prep_kernel      <<<dim3(NMIN / 4), dim3(256), 0, stream>>>(X, wsf);
  smote_main       <<<dim3(512),      dim3(256), 0, stream>>>(wsf);
  rerank_gen_kernel<<<dim3(NMIN / 4), dim3(256), 0, stream>>>(X, wsf, out);
  copy_kernel      <<<dim3(2048),     dim3(256), 0, stream>>>(X, y, out);
}